// Round 9
// baseline (634.753 us; speedup 1.0000x reference)
//
#include <hip/hip_runtime.h>
#include <hip/hip_bf16.h>

#define N_ROWS 8192
#define D_DIM  256

typedef __attribute__((ext_vector_type(8))) short bf16x8;
typedef __attribute__((ext_vector_type(4))) float f32x4;

__device__ __forceinline__ unsigned short f2bf(float x) {
    unsigned u = __float_as_uint(x);
    u = (u + 0x7FFFu + ((u >> 16) & 1u)) >> 16;
    return (unsigned short)u;
}
__device__ __forceinline__ float bf2f(unsigned short u) {
    return __uint_as_float(((unsigned)u) << 16);
}
__device__ __forceinline__ f32x4 mfma16(bf16x8 a, bf16x8 b, f32x4 c) {
    return __builtin_amdgcn_mfma_f32_16x16x32_bf16(a, b, c, 0, 0, 0);
}

// ---------------------------------------------------------------------------
// Kernel 0: prep (unchanged). blocks 0..127: x -> xhi/xlo + Xt (transposed).
// blocks 128..135: Wq/Wk -> hi/lo bf16.
// ---------------------------------------------------------------------------
__global__ __launch_bounds__(256) void prep_kernel(
    const float* __restrict__ x, const float* __restrict__ Wq, const float* __restrict__ Wk,
    unsigned short* __restrict__ xhi, unsigned short* __restrict__ xlo,
    unsigned short* __restrict__ Xt,
    unsigned short* __restrict__ Wqh, unsigned short* __restrict__ Wql,
    unsigned short* __restrict__ Wkh, unsigned short* __restrict__ Wkl)
{
    __shared__ unsigned short tile[64 * 256];
    int b = blockIdx.x, t = threadIdx.x;
    if (b < 128) {
        int rowbase = b * 64;
        int c = t >> 2, f0 = (t & 3) * 64;
        const float* xp = x + (size_t)(rowbase + c) * D_DIM + f0;
        size_t gbase = (size_t)(rowbase + c) * D_DIM + f0;
#pragma unroll
        for (int i = 0; i < 8; ++i) {
            float4 a4 = *(const float4*)(xp + 8 * i);
            float4 b4 = *(const float4*)(xp + 8 * i + 4);
            float v[8] = {a4.x, a4.y, a4.z, a4.w, b4.x, b4.y, b4.z, b4.w};
            bf16x8 hv, lv;
#pragma unroll
            for (int j = 0; j < 8; ++j) {
                unsigned short h = f2bf(v[j]);
                hv[j] = (short)h;
                lv[j] = (short)f2bf(v[j] - bf2f(h));
            }
            *(bf16x8*)(xhi + gbase + 8 * i) = hv;
            *(bf16x8*)(xlo + gbase + 8 * i) = lv;
            *(bf16x8*)(&tile[c * 256 + (((f0 + 8 * i) ^ ((c & 7) << 3)))]) = hv;
        }
        __syncthreads();
        int f = t;
        unsigned short vals[64];
#pragma unroll
        for (int c2 = 0; c2 < 64; ++c2)
            vals[c2] = tile[c2 * 256 + (f ^ ((c2 & 7) << 3))];
#pragma unroll
        for (int i = 0; i < 8; ++i) {
            bf16x8 pv;
#pragma unroll
            for (int j = 0; j < 8; ++j) pv[j] = (short)vals[8 * i + j];
            *(bf16x8*)(Xt + (size_t)f * N_ROWS + rowbase + 8 * i) = pv;
        }
    } else {
        int wb = b - 128;
        const float* src = (wb < 4) ? Wq : Wk;
        unsigned short* dh = (wb < 4) ? Wqh : Wkh;
        unsigned short* dl = (wb < 4) ? Wql : Wkl;
        int base = (wb & 3) * 16384;
#pragma unroll 4
        for (int i = 0; i < 64; ++i) {
            int idx = base + i * 256 + t;
            float v = src[idx];
            unsigned short h = f2bf(v);
            dh[idx] = h;
            dl[idx] = f2bf(v - bf2f(h));
        }
    }
}

// ---------------------------------------------------------------------------
// Kernel 1: y = x@W^T + b (split-bf16 MFMA) + Lorentz transform (unchanged).
// ---------------------------------------------------------------------------
__global__ __launch_bounds__(256) void qk_kernel(
    const unsigned short* __restrict__ xhi, const unsigned short* __restrict__ xlo,
    const unsigned short* __restrict__ Wh, const unsigned short* __restrict__ Wl,
    const float* __restrict__ bias, const float* __restrict__ logscale,
    unsigned short* __restrict__ Qb, float* __restrict__ q0)
{
    __shared__ float red[4][16];
    __shared__ float y0s[16];
    int tid = threadIdx.x;
    int lane = tid & 63, w = tid >> 6;
    int rowb = blockIdx.x * 16;
    int m = lane & 15, g = lane >> 4;

    bf16x8 ah[8], al[8];
    size_t abase = (size_t)(rowb + m) * D_DIM + g * 8;
#pragma unroll
    for (int k = 0; k < 8; ++k) {
        ah[k] = *(const bf16x8*)(xhi + abase + k * 32);
        al[k] = *(const bf16x8*)(xlo + abase + k * 32);
    }
    f32x4 acc[4];
#pragma unroll
    for (int fnl = 0; fnl < 4; ++fnl) {
        int fn = w * 4 + fnl;
        f32x4 a = (f32x4){0.f, 0.f, 0.f, 0.f};
        size_t wbase = (size_t)(fn * 16 + m) * D_DIM + g * 8;
#pragma unroll
        for (int k = 0; k < 8; ++k) {
            bf16x8 bh = *(const bf16x8*)(Wh + wbase + k * 32);
            bf16x8 bl = *(const bf16x8*)(Wl + wbase + k * 32);
            a = mfma16(ah[k], bh, a);
            a = mfma16(ah[k], bl, a);
            a = mfma16(al[k], bh, a);
        }
        float bv = bias[fn * 16 + m];
#pragma unroll
        for (int r = 0; r < 4; ++r) a[r] += bv;
        acc[fnl] = a;
    }
    float p[4];
#pragma unroll
    for (int r = 0; r < 4; ++r) {
        float s = 0.f;
#pragma unroll
        for (int fnl = 0; fnl < 4; ++fnl) { float v = acc[fnl][r]; s += v * v; }
        if (w == 0 && m == 0) s -= acc[0][r] * acc[0][r];   // exclude time col
        s += __shfl_xor(s, 1);
        s += __shfl_xor(s, 2);
        s += __shfl_xor(s, 4);
        s += __shfl_xor(s, 8);
        p[r] = s;
    }
    if (m == 0) {
#pragma unroll
        for (int r = 0; r < 4; ++r) red[w][g * 4 + r] = p[r];
        if (w == 0)
#pragma unroll
            for (int r = 0; r < 4; ++r) y0s[g * 4 + r] = acc[0][r];
    }
    __syncthreads();
    float es = __expf(logscale[0]);
#pragma unroll
    for (int r = 0; r < 4; ++r) {
        int rr = g * 4 + r;
        float ssq = red[0][rr] + red[1][rr] + red[2][rr] + red[3][rr];
        float y0 = y0s[rr];
        float tt = es * __builtin_amdgcn_rcpf(1.f + __expf(-y0)) + 1.1f;
        float sc = sqrtf((tt * tt - 1.f) * __builtin_amdgcn_rcpf(fmaxf(ssq, 1e-8f)));
        int row = rowb + rr;
#pragma unroll
        for (int fnl = 0; fnl < 4; ++fnl) {
            int fn = w * 4 + fnl;
            float v = acc[fnl][r] * sc;
            Qb[(size_t)row * D_DIM + fn * 16 + m] =
                (fn == 0 && m == 0) ? (unsigned short)0 : f2bf(v);
        }
        if (w == 0 && m == 0) q0[row] = tt;
    }
}

// ---------------------------------------------------------------------------
// Kernel 2: fused att — identical body to round 8 EXCEPT the grid transpose:
// blockIdx.x = col-chunk (8), blockIdx.y = row-block (64). With x-fastest
// dispatch and XCD = n%8, all 64 blocks of a chunk land on ONE XCD and the
// two co-resident blocks on a CU share the SAME chunk -> per-XCD L2 holds the
// whole chunk working set (~1 MB), killing the 512MB staging re-fetch.
// ---------------------------------------------------------------------------
__global__ __launch_bounds__(512, 4) void att_kernel(
    const unsigned short* __restrict__ Qb, const unsigned short* __restrict__ Kb,
    const float* __restrict__ q0, const float* __restrict__ k0,
    const unsigned short* __restrict__ Xt,
    const float* __restrict__ p_scale, const float* __restrict__ p_bias,
    float* __restrict__ att_out, float* __restrict__ partial, int chunkW)
{
    __shared__ unsigned short Ks[64 * 256];  // 32KB; first 16KB reused as As[128][64]
    __shared__ unsigned short Xs[256 * 64];  // 32KB
    int tid = threadIdx.x;
    int lane = tid & 63, wid = tid >> 6;
    int wm = wid >> 1, wn = wid & 1;        // 4 row-groups x 2 col-groups
    int m16 = lane & 15, g = lane >> 4;
    int rowbase = blockIdx.y * 128;         // TRANSPOSED: y = row-block
    int colbase = blockIdx.x * chunkW;      // TRANSPOSED: x = chunk
    float c1 = 2.0f / p_scale[0];
    float c0 = c1 + p_bias[0];

    // Q fragments (B-operand of swapped S): 32 rows per wave
    bf16x8 qa[2][8];
#pragma unroll
    for (int mi = 0; mi < 2; ++mi) {
        size_t base = (size_t)(rowbase + wm * 32 + mi * 16 + m16) * D_DIM + g * 8;
#pragma unroll
        for (int k = 0; k < 8; ++k)
            qa[mi][k] = *(const bf16x8*)(Qb + base + k * 32);
    }
    float q0v[2];
#pragma unroll
    for (int mi = 0; mi < 2; ++mi)
        q0v[mi] = q0[rowbase + wm * 32 + mi * 16 + m16];

    f32x4 oacc[2][8];
#pragma unroll
    for (int mi = 0; mi < 2; ++mi)
#pragma unroll
        for (int n = 0; n < 8; ++n)
            oacc[mi][n] = (f32x4){0.f, 0.f, 0.f, 0.f};

    int nstrips = chunkW / 64;
    int sc = tid >> 3, sko = (tid & 7) * 32;   // K staging: 64B per thread
    int sf = tid >> 1, sco = (tid & 1) * 32;   // Xt staging: 64B per thread
    unsigned short* As = Ks;                   // alias: att[128][64] bf16 (16KB)

    for (int s = 0; s < nstrips; ++s) {
        int cb = colbase + s * 64;
        if (s) __syncthreads();                 // prev PV done with As/Xs
        {
            const unsigned short* srcK = Kb + (size_t)(cb + sc) * D_DIM + sko;
            unsigned short* dK = Ks + sc * 256;
            int swK = (sc & 7) << 3;
#pragma unroll
            for (int i = 0; i < 4; ++i)
                *(bf16x8*)(dK + ((sko + 8 * i) ^ swK)) = *(const bf16x8*)(srcK + 8 * i);
            const unsigned short* srcX = Xt + (size_t)sf * N_ROWS + cb + sco;
            unsigned short* dX = Xs + sf * 64;
            int swX = (sf & 7) << 3;
#pragma unroll
            for (int i = 0; i < 4; ++i)
                *(bf16x8*)(dX + ((sco + 8 * i) ^ swX)) = *(const bf16x8*)(srcX + 8 * i);
        }
        __syncthreads();                        // tiles staged

        // S^T per wave: kcols (wn*32+fn*16+g*4+r) x qrows (wm*32+mi*16+m16)
        f32x4 sacc[2][2];
#pragma unroll
        for (int mi = 0; mi < 2; ++mi)
#pragma unroll
            for (int fn = 0; fn < 2; ++fn)
                sacc[mi][fn] = (f32x4){0.f, 0.f, 0.f, 0.f};
#pragma unroll
        for (int k = 0; k < 8; ++k) {
            bf16x8 kb[2];
#pragma unroll
            for (int fn = 0; fn < 2; ++fn) {
                int krow = wn * 32 + fn * 16 + m16;
                kb[fn] = *(const bf16x8*)(Ks + krow * 256 + ((k * 32 + g * 8) ^ ((krow & 7) << 3)));
            }
#pragma unroll
            for (int mi = 0; mi < 2; ++mi)
#pragma unroll
                for (int fn = 0; fn < 2; ++fn)
                    sacc[mi][fn] = mfma16(kb[fn], qa[mi][k], sacc[mi][fn]);
        }
        __syncthreads();                        // all Ks reads done (alias safe)

        // epilogue: cin -> sigmoid; float4 att stores; packed uint2 As writes
        float4 k0v[2];
#pragma unroll
        for (int fn = 0; fn < 2; ++fn)
            k0v[fn] = *(const float4*)(k0 + cb + wn * 32 + fn * 16 + g * 4);
#pragma unroll
        for (int mi = 0; mi < 2; ++mi) {
            int qrow = wm * 32 + mi * 16 + m16;
#pragma unroll
            for (int fn = 0; fn < 2; ++fn) {
                float av[4];
#pragma unroll
                for (int r = 0; r < 4; ++r) {
                    float cin = sacc[mi][fn][r] - q0v[mi] * (&k0v[fn].x)[r];
                    float z = c0 + c1 * cin;
                    av[r] = __builtin_amdgcn_rcpf(1.f + __expf(-z));
                }
                int col = wn * 32 + fn * 16 + g * 4;
                *(float4*)(att_out + (size_t)(rowbase + qrow) * N_ROWS + cb + col) =
                    (float4){av[0], av[1], av[2], av[3]};
                uint2 pk;
                pk.x = (unsigned)f2bf(av[0]) | ((unsigned)f2bf(av[1]) << 16);
                pk.y = (unsigned)f2bf(av[2]) | ((unsigned)f2bf(av[3]) << 16);
                *(uint2*)(As + qrow * 64 + (col ^ ((qrow & 7) << 3))) = pk;
            }
        }
        __syncthreads();                        // As visible

        // PV: O[128][256] += att[128][64] @ X[64][256]; wave: 32 rows x 128 feats
#pragma unroll
        for (int kf = 0; kf < 2; ++kf) {
            bf16x8 pa[2];
#pragma unroll
            for (int mi = 0; mi < 2; ++mi) {
                int row = wm * 32 + mi * 16 + m16;
                pa[mi] = *(const bf16x8*)(As + row * 64 + (((kf * 32 + g * 8)) ^ ((row & 7) << 3)));
            }
#pragma unroll
            for (int n = 0; n < 8; ++n) {
                int f = wn * 128 + n * 16 + m16;
                bf16x8 xb = *(const bf16x8*)(Xs + f * 64 + (((kf * 32 + g * 8)) ^ ((f & 7) << 3)));
#pragma unroll
                for (int mi = 0; mi < 2; ++mi)
                    oacc[mi][n] = mfma16(pa[mi], xb, oacc[mi][n]);
            }
        }
    }

    // write partial support for this col-chunk (chunk index = blockIdx.x now)
    float* pbase = partial + (size_t)blockIdx.x * N_ROWS * D_DIM;
#pragma unroll
    for (int mi = 0; mi < 2; ++mi)
#pragma unroll
        for (int n = 0; n < 8; ++n)
#pragma unroll
            for (int r = 0; r < 4; ++r) {
                int row = rowbase + wm * 32 + mi * 16 + g * 4 + r;
                int f = wn * 128 + n * 16 + m16;
                pbase[(size_t)row * D_DIM + f] = oacc[mi][n][r];
            }
}

// ---------------------------------------------------------------------------
// Kernel 3: reduce partials + Lorentz normalize (unchanged).
// ---------------------------------------------------------------------------
__global__ __launch_bounds__(64) void norm_kernel(
    const float* __restrict__ partial, float* __restrict__ outp, int nchunk)
{
    int row = blockIdx.x, lane = threadIdx.x;
    float a0 = 0.f, a1 = 0.f, a2 = 0.f, a3 = 0.f;
    for (int p = 0; p < nchunk; ++p) {
        const float4 v = *(const float4*)(partial + ((size_t)p * N_ROWS + row) * D_DIM + lane * 4);
        a0 += v.x; a1 += v.y; a2 += v.z; a3 += v.w;
    }
    float sq = a0 * a0 + a1 * a1 + a2 * a2 + a3 * a3;
#pragma unroll
    for (int off = 1; off < 64; off <<= 1) sq += __shfl_xor(sq, off);
    float s0 = __shfl(a0, 0);
    float neg = 2.f * s0 * s0 - sq;
    float dn = sqrtf(fmaxf(fabsf(neg), 1e-8f));
    float inv = 1.f / dn;
    float4 o;
    o.x = a0 * inv; o.y = a1 * inv; o.z = a2 * inv; o.w = a3 * inv;
    *(float4*)(outp + (size_t)row * D_DIM + lane * 4) = o;
}

// ---------------------------------------------------------------------------
extern "C" void kernel_launch(void* const* d_in, const int* in_sizes, int n_in,
                              void* d_out, int out_size, void* d_ws, size_t ws_size,
                              hipStream_t stream)
{
    const float* x         = (const float*)d_in[0];
    const float* Wq        = (const float*)d_in[1];
    const float* bq        = (const float*)d_in[2];
    const float* sq_log    = (const float*)d_in[3];
    const float* Wk        = (const float*)d_in[4];
    const float* bk        = (const float*)d_in[5];
    const float* sk_log    = (const float*)d_in[6];
    const float* att_bias  = (const float*)d_in[7];
    const float* att_scale = (const float*)d_in[8];
    float* outp    = (float*)d_out;
    float* att_out = outp + (size_t)N_ROWS * D_DIM;

    char* w = (char*)d_ws;
    size_t used = 0;
    auto alloc = [&](size_t bytes) -> char* {
        char* p = w + used;
        used += (bytes + 255) & ~(size_t)255;
        return p;
    };
    unsigned short* xhi = (unsigned short*)alloc((size_t)N_ROWS * D_DIM * 2);
    unsigned short* xlo = (unsigned short*)alloc((size_t)N_ROWS * D_DIM * 2);
    unsigned short* XtB = (unsigned short*)alloc((size_t)N_ROWS * D_DIM * 2);
    unsigned short* Wqh = (unsigned short*)alloc((size_t)65536 * 2);
    unsigned short* Wql = (unsigned short*)alloc((size_t)65536 * 2);
    unsigned short* Wkh = (unsigned short*)alloc((size_t)65536 * 2);
    unsigned short* Wkl = (unsigned short*)alloc((size_t)65536 * 2);
    unsigned short* QbB = (unsigned short*)alloc((size_t)N_ROWS * D_DIM * 2);
    unsigned short* KbB = (unsigned short*)alloc((size_t)N_ROWS * D_DIM * 2);
    float* q0v = (float*)alloc((size_t)N_ROWS * 4);
    float* k0v = (float*)alloc((size_t)N_ROWS * 4);

    int nchunk = 8;   // 8 chunks x 64 row-blocks = 512 blocks; chunk == XCD
    while (nchunk > 1 &&
           used + (size_t)nchunk * N_ROWS * D_DIM * 4 > ws_size)
        nchunk >>= 1;
    float* partial = (float*)alloc((size_t)nchunk * N_ROWS * D_DIM * 4);

    hipLaunchKernelGGL(prep_kernel, dim3(136), dim3(256), 0, stream,
                       x, Wq, Wk, xhi, xlo, XtB, Wqh, Wql, Wkh, Wkl);
    hipLaunchKernelGGL(qk_kernel, dim3(N_ROWS / 16), dim3(256), 0, stream,
                       xhi, xlo, Wqh, Wql, bq, sq_log, QbB, q0v);
    hipLaunchKernelGGL(qk_kernel, dim3(N_ROWS / 16), dim3(256), 0, stream,
                       xhi, xlo, Wkh, Wkl, bk, sk_log, KbB, k0v);
    int chunkW = N_ROWS / nchunk;
    hipLaunchKernelGGL(att_kernel, dim3(nchunk, N_ROWS / 128), dim3(512), 0, stream,
                       QbB, KbB, q0v, k0v, XtB, att_scale, att_bias,
                       att_out, partial, chunkW);
    hipLaunchKernelGGL(norm_kernel, dim3(N_ROWS), dim3(64), 0, stream,
                       partial, outp, nchunk);
}

// Round 13
// 433.203 us; speedup vs baseline: 1.4653x; 1.4653x over previous
//
#include <hip/hip_runtime.h>
#include <hip/hip_bf16.h>

#define N_ROWS 8192
#define D_DIM  256

typedef __attribute__((ext_vector_type(8))) short bf16x8;
typedef __attribute__((ext_vector_type(4))) float f32x4;

__device__ __forceinline__ unsigned short f2bf(float x) {
    unsigned u = __float_as_uint(x);
    u = (u + 0x7FFFu + ((u >> 16) & 1u)) >> 16;
    return (unsigned short)u;
}
__device__ __forceinline__ float bf2f(unsigned short u) {
    return __uint_as_float(((unsigned)u) << 16);
}
__device__ __forceinline__ f32x4 mfma16(bf16x8 a, bf16x8 b, f32x4 c) {
    return __builtin_amdgcn_mfma_f32_16x16x32_bf16(a, b, c, 0, 0, 0);
}

// ---------------------------------------------------------------------------
// Kernel 0: prep (unchanged). blocks 0..127: x -> xhi/xlo + Xt (transposed).
// blocks 128..135: Wq/Wk -> hi/lo bf16.
// ---------------------------------------------------------------------------
__global__ __launch_bounds__(256) void prep_kernel(
    const float* __restrict__ x, const float* __restrict__ Wq, const float* __restrict__ Wk,
    unsigned short* __restrict__ xhi, unsigned short* __restrict__ xlo,
    unsigned short* __restrict__ Xt,
    unsigned short* __restrict__ Wqh, unsigned short* __restrict__ Wql,
    unsigned short* __restrict__ Wkh, unsigned short* __restrict__ Wkl)
{
    __shared__ unsigned short tile[64 * 256];
    int b = blockIdx.x, t = threadIdx.x;
    if (b < 128) {
        int rowbase = b * 64;
        int c = t >> 2, f0 = (t & 3) * 64;
        const float* xp = x + (size_t)(rowbase + c) * D_DIM + f0;
        size_t gbase = (size_t)(rowbase + c) * D_DIM + f0;
#pragma unroll
        for (int i = 0; i < 8; ++i) {
            float4 a4 = *(const float4*)(xp + 8 * i);
            float4 b4 = *(const float4*)(xp + 8 * i + 4);
            float v[8] = {a4.x, a4.y, a4.z, a4.w, b4.x, b4.y, b4.z, b4.w};
            bf16x8 hv, lv;
#pragma unroll
            for (int j = 0; j < 8; ++j) {
                unsigned short h = f2bf(v[j]);
                hv[j] = (short)h;
                lv[j] = (short)f2bf(v[j] - bf2f(h));
            }
            *(bf16x8*)(xhi + gbase + 8 * i) = hv;
            *(bf16x8*)(xlo + gbase + 8 * i) = lv;
            *(bf16x8*)(&tile[c * 256 + (((f0 + 8 * i) ^ ((c & 7) << 3)))]) = hv;
        }
        __syncthreads();
        int f = t;
        unsigned short vals[64];
#pragma unroll
        for (int c2 = 0; c2 < 64; ++c2)
            vals[c2] = tile[c2 * 256 + (f ^ ((c2 & 7) << 3))];
#pragma unroll
        for (int i = 0; i < 8; ++i) {
            bf16x8 pv;
#pragma unroll
            for (int j = 0; j < 8; ++j) pv[j] = (short)vals[8 * i + j];
            *(bf16x8*)(Xt + (size_t)f * N_ROWS + rowbase + 8 * i) = pv;
        }
    } else {
        int wb = b - 128;
        const float* src = (wb < 4) ? Wq : Wk;
        unsigned short* dh = (wb < 4) ? Wqh : Wkh;
        unsigned short* dl = (wb < 4) ? Wql : Wkl;
        int base = (wb & 3) * 16384;
#pragma unroll 4
        for (int i = 0; i < 64; ++i) {
            int idx = base + i * 256 + t;
            float v = src[idx];
            unsigned short h = f2bf(v);
            dh[idx] = h;
            dl[idx] = f2bf(v - bf2f(h));
        }
    }
}

// ---------------------------------------------------------------------------
// Kernel 1: y = x@W^T + b (split-bf16 MFMA) + Lorentz transform (unchanged).
// ---------------------------------------------------------------------------
__global__ __launch_bounds__(256) void qk_kernel(
    const unsigned short* __restrict__ xhi, const unsigned short* __restrict__ xlo,
    const unsigned short* __restrict__ Wh, const unsigned short* __restrict__ Wl,
    const float* __restrict__ bias, const float* __restrict__ logscale,
    unsigned short* __restrict__ Qb, float* __restrict__ q0)
{
    __shared__ float red[4][16];
    __shared__ float y0s[16];
    int tid = threadIdx.x;
    int lane = tid & 63, w = tid >> 6;
    int rowb = blockIdx.x * 16;
    int m = lane & 15, g = lane >> 4;

    bf16x8 ah[8], al[8];
    size_t abase = (size_t)(rowb + m) * D_DIM + g * 8;
#pragma unroll
    for (int k = 0; k < 8; ++k) {
        ah[k] = *(const bf16x8*)(xhi + abase + k * 32);
        al[k] = *(const bf16x8*)(xlo + abase + k * 32);
    }
    f32x4 acc[4];
#pragma unroll
    for (int fnl = 0; fnl < 4; ++fnl) {
        int fn = w * 4 + fnl;
        f32x4 a = (f32x4){0.f, 0.f, 0.f, 0.f};
        size_t wbase = (size_t)(fn * 16 + m) * D_DIM + g * 8;
#pragma unroll
        for (int k = 0; k < 8; ++k) {
            bf16x8 bh = *(const bf16x8*)(Wh + wbase + k * 32);
            bf16x8 bl = *(const bf16x8*)(Wl + wbase + k * 32);
            a = mfma16(ah[k], bh, a);
            a = mfma16(ah[k], bl, a);
            a = mfma16(al[k], bh, a);
        }
        float bv = bias[fn * 16 + m];
#pragma unroll
        for (int r = 0; r < 4; ++r) a[r] += bv;
        acc[fnl] = a;
    }
    float p[4];
#pragma unroll
    for (int r = 0; r < 4; ++r) {
        float s = 0.f;
#pragma unroll
        for (int fnl = 0; fnl < 4; ++fnl) { float v = acc[fnl][r]; s += v * v; }
        if (w == 0 && m == 0) s -= acc[0][r] * acc[0][r];   // exclude time col
        s += __shfl_xor(s, 1);
        s += __shfl_xor(s, 2);
        s += __shfl_xor(s, 4);
        s += __shfl_xor(s, 8);
        p[r] = s;
    }
    if (m == 0) {
#pragma unroll
        for (int r = 0; r < 4; ++r) red[w][g * 4 + r] = p[r];
        if (w == 0)
#pragma unroll
            for (int r = 0; r < 4; ++r) y0s[g * 4 + r] = acc[0][r];
    }
    __syncthreads();
    float es = __expf(logscale[0]);
#pragma unroll
    for (int r = 0; r < 4; ++r) {
        int rr = g * 4 + r;
        float ssq = red[0][rr] + red[1][rr] + red[2][rr] + red[3][rr];
        float y0 = y0s[rr];
        float tt = es * __builtin_amdgcn_rcpf(1.f + __expf(-y0)) + 1.1f;
        float sc = sqrtf((tt * tt - 1.f) * __builtin_amdgcn_rcpf(fmaxf(ssq, 1e-8f)));
        int row = rowb + rr;
#pragma unroll
        for (int fnl = 0; fnl < 4; ++fnl) {
            int fn = w * 4 + fnl;
            float v = acc[fnl][r] * sc;
            Qb[(size_t)row * D_DIM + fn * 16 + m] =
                (fn == 0 && m == 0) ? (unsigned short)0 : f2bf(v);
        }
        if (w == 0 && m == 0) q0[row] = tt;
    }
}

// ---------------------------------------------------------------------------
// Kernel 2: fused att. R6 dispatch geometry (grid (64,4), 128-row blocks,
// 1 block/CU -> lockstep L2 reuse, FETCH~35MB proven) + swapped-S float4
// stores + packed uint2 As + cheap sigmoid. As is now a SEPARATE padded LDS
// array ([128][72]): total LDS 82KB forces 1 block/CU structurally, removes
// the Ks-alias barrier (3 barriers/strip), and pad kills PV bank conflicts.
// ---------------------------------------------------------------------------
__global__ __launch_bounds__(512, 2) void att_kernel(
    const unsigned short* __restrict__ Qb, const unsigned short* __restrict__ Kb,
    const float* __restrict__ q0, const float* __restrict__ k0,
    const unsigned short* __restrict__ Xt,
    const float* __restrict__ p_scale, const float* __restrict__ p_bias,
    float* __restrict__ att_out, float* __restrict__ partial, int chunkW)
{
    __shared__ unsigned short Ks[64 * 256];   // 32KB
    __shared__ unsigned short Xs[256 * 64];   // 32KB
    __shared__ unsigned short As[128 * 72];   // 18KB padded att tile (total 82KB)
    int tid = threadIdx.x;
    int lane = tid & 63, wid = tid >> 6;
    int wm = wid >> 1, wn = wid & 1;        // 4 row-groups x 2 col-groups
    int m16 = lane & 15, g = lane >> 4;
    int rowbase = blockIdx.x * 128;
    int colbase = blockIdx.y * chunkW;
    float c1 = 2.0f / p_scale[0];
    float c0 = c1 + p_bias[0];

    // Q fragments (B-operand of swapped S): 32 rows per wave
    bf16x8 qa[2][8];
#pragma unroll
    for (int mi = 0; mi < 2; ++mi) {
        size_t base = (size_t)(rowbase + wm * 32 + mi * 16 + m16) * D_DIM + g * 8;
#pragma unroll
        for (int k = 0; k < 8; ++k)
            qa[mi][k] = *(const bf16x8*)(Qb + base + k * 32);
    }
    float q0v[2];
#pragma unroll
    for (int mi = 0; mi < 2; ++mi)
        q0v[mi] = q0[rowbase + wm * 32 + mi * 16 + m16];

    f32x4 oacc[2][8];
#pragma unroll
    for (int mi = 0; mi < 2; ++mi)
#pragma unroll
        for (int n = 0; n < 8; ++n)
            oacc[mi][n] = (f32x4){0.f, 0.f, 0.f, 0.f};

    int nstrips = chunkW / 64;
    int sc = tid >> 3, sko = (tid & 7) * 32;   // K staging: 64B per thread
    int sf = tid >> 1, sco = (tid & 1) * 32;   // Xt staging: 64B per thread

    for (int s = 0; s < nstrips; ++s) {
        int cb = colbase + s * 64;
        if (s) __syncthreads();                 // prev PV done with As/Xs
        {
            const unsigned short* srcK = Kb + (size_t)(cb + sc) * D_DIM + sko;
            unsigned short* dK = Ks + sc * 256;
            int swK = (sc & 7) << 3;
#pragma unroll
            for (int i = 0; i < 4; ++i)
                *(bf16x8*)(dK + ((sko + 8 * i) ^ swK)) = *(const bf16x8*)(srcK + 8 * i);
            const unsigned short* srcX = Xt + (size_t)sf * N_ROWS + cb + sco;
            unsigned short* dX = Xs + sf * 64;
            int swX = (sf & 7) << 3;
#pragma unroll
            for (int i = 0; i < 4; ++i)
                *(bf16x8*)(dX + ((sco + 8 * i) ^ swX)) = *(const bf16x8*)(srcX + 8 * i);
        }
        __syncthreads();                        // tiles staged

        // S^T per wave: kcols (wn*32+fn*16+g*4+r) x qrows (wm*32+mi*16+m16)
        f32x4 sacc[2][2];
#pragma unroll
        for (int mi = 0; mi < 2; ++mi)
#pragma unroll
            for (int fn = 0; fn < 2; ++fn)
                sacc[mi][fn] = (f32x4){0.f, 0.f, 0.f, 0.f};
#pragma unroll
        for (int k = 0; k < 8; ++k) {
            bf16x8 kb[2];
#pragma unroll
            for (int fn = 0; fn < 2; ++fn) {
                int krow = wn * 32 + fn * 16 + m16;
                kb[fn] = *(const bf16x8*)(Ks + krow * 256 + ((k * 32 + g * 8) ^ ((krow & 7) << 3)));
            }
#pragma unroll
            for (int mi = 0; mi < 2; ++mi)
#pragma unroll
                for (int fn = 0; fn < 2; ++fn)
                    sacc[mi][fn] = mfma16(kb[fn], qa[mi][k], sacc[mi][fn]);
        }
        // NOTE: no barrier here — As no longer aliases Ks.

        // epilogue: cin -> sigmoid; float4 att stores; packed uint2 As writes
        float4 k0v[2];
#pragma unroll
        for (int fn = 0; fn < 2; ++fn)
            k0v[fn] = *(const float4*)(k0 + cb + wn * 32 + fn * 16 + g * 4);
#pragma unroll
        for (int mi = 0; mi < 2; ++mi) {
            int qrow = wm * 32 + mi * 16 + m16;
#pragma unroll
            for (int fn = 0; fn < 2; ++fn) {
                float av[4];
#pragma unroll
                for (int r = 0; r < 4; ++r) {
                    float cin = sacc[mi][fn][r] - q0v[mi] * (&k0v[fn].x)[r];
                    float z = c0 + c1 * cin;
                    av[r] = __builtin_amdgcn_rcpf(1.f + __expf(-z));
                }
                int col = wn * 32 + fn * 16 + g * 4;
                *(float4*)(att_out + (size_t)(rowbase + qrow) * N_ROWS + cb + col) =
                    (float4){av[0], av[1], av[2], av[3]};
                uint2 pk;
                pk.x = (unsigned)f2bf(av[0]) | ((unsigned)f2bf(av[1]) << 16);
                pk.y = (unsigned)f2bf(av[2]) | ((unsigned)f2bf(av[3]) << 16);
                *(uint2*)(As + qrow * 72 + (col ^ ((qrow & 7) << 3))) = pk;
            }
        }
        __syncthreads();                        // As visible

        // PV: O[128][256] += att[128][64] @ X[64][256]; wave: 32 rows x 128 feats
#pragma unroll
        for (int kf = 0; kf < 2; ++kf) {
            bf16x8 pa[2];
#pragma unroll
            for (int mi = 0; mi < 2; ++mi) {
                int row = wm * 32 + mi * 16 + m16;
                pa[mi] = *(const bf16x8*)(As + row * 72 + (((kf * 32 + g * 8)) ^ ((row & 7) << 3)));
            }
#pragma unroll
            for (int n = 0; n < 8; ++n) {
                int f = wn * 128 + n * 16 + m16;
                bf16x8 xb = *(const bf16x8*)(Xs + f * 64 + (((kf * 32 + g * 8)) ^ ((f & 7) << 3)));
#pragma unroll
                for (int mi = 0; mi < 2; ++mi)
                    oacc[mi][n] = mfma16(pa[mi], xb, oacc[mi][n]);
            }
        }
    }

    // write partial support for this col-chunk
    float* pbase = partial + (size_t)blockIdx.y * N_ROWS * D_DIM;
#pragma unroll
    for (int mi = 0; mi < 2; ++mi)
#pragma unroll
        for (int n = 0; n < 8; ++n)
#pragma unroll
            for (int r = 0; r < 4; ++r) {
                int row = rowbase + wm * 32 + mi * 16 + g * 4 + r;
                int f = wn * 128 + n * 16 + m16;
                pbase[(size_t)row * D_DIM + f] = oacc[mi][n][r];
            }
}

// ---------------------------------------------------------------------------
// Kernel 3: reduce partials + Lorentz normalize (unchanged).
// ---------------------------------------------------------------------------
__global__ __launch_bounds__(64) void norm_kernel(
    const float* __restrict__ partial, float* __restrict__ outp, int nchunk)
{
    int row = blockIdx.x, lane = threadIdx.x;
    float a0 = 0.f, a1 = 0.f, a2 = 0.f, a3 = 0.f;
    for (int p = 0; p < nchunk; ++p) {
        const float4 v = *(const float4*)(partial + ((size_t)p * N_ROWS + row) * D_DIM + lane * 4);
        a0 += v.x; a1 += v.y; a2 += v.z; a3 += v.w;
    }
    float sq = a0 * a0 + a1 * a1 + a2 * a2 + a3 * a3;
#pragma unroll
    for (int off = 1; off < 64; off <<= 1) sq += __shfl_xor(sq, off);
    float s0 = __shfl(a0, 0);
    float neg = 2.f * s0 * s0 - sq;
    float dn = sqrtf(fmaxf(fabsf(neg), 1e-8f));
    float inv = 1.f / dn;
    float4 o;
    o.x = a0 * inv; o.y = a1 * inv; o.z = a2 * inv; o.w = a3 * inv;
    *(float4*)(outp + (size_t)row * D_DIM + lane * 4) = o;
}

// ---------------------------------------------------------------------------
extern "C" void kernel_launch(void* const* d_in, const int* in_sizes, int n_in,
                              void* d_out, int out_size, void* d_ws, size_t ws_size,
                              hipStream_t stream)
{
    const float* x         = (const float*)d_in[0];
    const float* Wq        = (const float*)d_in[1];
    const float* bq        = (const float*)d_in[2];
    const float* sq_log    = (const float*)d_in[3];
    const float* Wk        = (const float*)d_in[4];
    const float* bk        = (const float*)d_in[5];
    const float* sk_log    = (const float*)d_in[6];
    const float* att_bias  = (const float*)d_in[7];
    const float* att_scale = (const float*)d_in[8];
    float* outp    = (float*)d_out;
    float* att_out = outp + (size_t)N_ROWS * D_DIM;

    char* w = (char*)d_ws;
    size_t used = 0;
    auto alloc = [&](size_t bytes) -> char* {
        char* p = w + used;
        used += (bytes + 255) & ~(size_t)255;
        return p;
    };
    unsigned short* xhi = (unsigned short*)alloc((size_t)N_ROWS * D_DIM * 2);
    unsigned short* xlo = (unsigned short*)alloc((size_t)N_ROWS * D_DIM * 2);
    unsigned short* XtB = (unsigned short*)alloc((size_t)N_ROWS * D_DIM * 2);
    unsigned short* Wqh = (unsigned short*)alloc((size_t)65536 * 2);
    unsigned short* Wql = (unsigned short*)alloc((size_t)65536 * 2);
    unsigned short* Wkh = (unsigned short*)alloc((size_t)65536 * 2);
    unsigned short* Wkl = (unsigned short*)alloc((size_t)65536 * 2);
    unsigned short* QbB = (unsigned short*)alloc((size_t)N_ROWS * D_DIM * 2);
    unsigned short* KbB = (unsigned short*)alloc((size_t)N_ROWS * D_DIM * 2);
    float* q0v = (float*)alloc((size_t)N_ROWS * 4);
    float* k0v = (float*)alloc((size_t)N_ROWS * 4);

    int nchunk = 4;   // grid (64 x 4) = 256 blocks = 1 block/CU (R6-proven)
    while (nchunk > 1 &&
           used + (size_t)nchunk * N_ROWS * D_DIM * 4 > ws_size)
        nchunk >>= 1;
    float* partial = (float*)alloc((size_t)nchunk * N_ROWS * D_DIM * 4);

    hipLaunchKernelGGL(prep_kernel, dim3(136), dim3(256), 0, stream,
                       x, Wq, Wk, xhi, xlo, XtB, Wqh, Wql, Wkh, Wkl);
    hipLaunchKernelGGL(qk_kernel, dim3(N_ROWS / 16), dim3(256), 0, stream,
                       xhi, xlo, Wqh, Wql, bq, sq_log, QbB, q0v);
    hipLaunchKernelGGL(qk_kernel, dim3(N_ROWS / 16), dim3(256), 0, stream,
                       xhi, xlo, Wkh, Wkl, bk, sk_log, KbB, k0v);
    int chunkW = N_ROWS / nchunk;
    hipLaunchKernelGGL(att_kernel, dim3(N_ROWS / 128, nchunk), dim3(512), 0, stream,
                       QbB, KbB, q0v, k0v, XtB, att_scale, att_bias,
                       att_out, partial, chunkW);
    hipLaunchKernelGGL(norm_kernel, dim3(N_ROWS), dim3(64), 0, stream,
                       partial, outp, nchunk);
}